// Round 5
// baseline (544.170 us; speedup 1.0000x reference)
//
#include <hip/hip_runtime.h>
#include <hip/hip_bf16.h>
#include <stdint.h>

#define N_HEADC 12
#define T_SEQ   2048
#define C_EMBD  768
#define HD      64

typedef short s16x8 __attribute__((ext_vector_type(8)));
typedef float f32x4 __attribute__((ext_vector_type(4)));
typedef unsigned short u16;
typedef unsigned int   u32;
typedef unsigned long long u64;

// fp32 -> bf16 round-to-nearest-even
__device__ __forceinline__ u16 f2bf(float f) {
  u32 u = __builtin_bit_cast(u32, f);
  u32 r = (u + 0x7FFFu + ((u >> 16) & 1u)) >> 16;
  return (u16)r;
}

// async 16B global->LDS (dest = wave-uniform base + lane*16)
__device__ __forceinline__ void async16(const void* g, void* l) {
  u64 ga = (u64)g;
  u32 la = (u32)(u64)l;
  __builtin_amdgcn_global_load_lds(
      (const __attribute__((address_space(1))) u32*)ga,
      (__attribute__((address_space(3))) u32*)la, 16, 0, 0);
}

// ---------------- fused prep: cvt + both weight transposes ----------------

__global__ __launch_bounds__(256) void k_prep(
    const float4* __restrict__ x4, ushort4* __restrict__ xb4,
    const float* __restrict__ Wa, u16* __restrict__ wat,
    const float* __restrict__ Wp, u16* __restrict__ wpt) {
  __shared__ float tl[64 * 65];
  int bx = blockIdx.x;
  int tid = threadIdx.x;
  if (bx < 6144) {
    int i = bx * 256 + tid;
    float4 v = x4[i];
    ushort4 o;
    o.x = f2bf(v.x); o.y = f2bf(v.y); o.z = f2bf(v.z); o.w = f2bf(v.w);
    xb4[i] = o;
    return;
  }
  const float* in; u16* out; int Kdim, Ndim, n0, k0;
  if (bx < 6144 + 432) {
    int idx = bx - 6144;
    in = Wa; out = wat; Kdim = C_EMBD; Ndim = 3 * C_EMBD;
    n0 = (idx % 36) * 64; k0 = (idx / 36) * 64;
  } else {
    int idx = bx - 6576;
    in = Wp; out = wpt; Kdim = C_EMBD; Ndim = C_EMBD;
    n0 = (idx % 12) * 64; k0 = (idx / 12) * 64;
  }
  int r0 = tid >> 4;
  int cb = (tid & 15) * 4;
#pragma unroll
  for (int g = 0; g < 4; ++g) {
    int r = r0 + g * 16;
    float4 v = *(const float4*)&in[(size_t)(k0 + r) * Ndim + n0 + cb];
    tl[r * 65 + cb + 0] = v.x;
    tl[r * 65 + cb + 1] = v.y;
    tl[r * 65 + cb + 2] = v.z;
    tl[r * 65 + cb + 3] = v.w;
  }
  __syncthreads();
  int rr0 = tid >> 3;
  int cc = (tid & 7) * 8;
#pragma unroll
  for (int g = 0; g < 2; ++g) {
    int rr = rr0 + g * 32;
    u16 tmp[8];
#pragma unroll
    for (int j = 0; j < 8; ++j) tmp[j] = f2bf(tl[(cc + j) * 65 + rr]);
    *(uint4*)&out[(size_t)(n0 + rr) * Kdim + k0 + cc] = *(uint4*)tmp;
  }
}

// vt[bh][d][t] = v[bh][t][d], bf16, 64x64 tiles (stride-65 LDS: conflict-free)
__global__ __launch_bounds__(256) void k_transpose_v(const u16* __restrict__ v,
                                                     u16* __restrict__ vt) {
  __shared__ u16 tl[64 * 65];
  int t0 = blockIdx.x * 64;
  int bh = blockIdx.y;
  int tid = threadIdx.x;
  const u16* vb = v + (size_t)bh * T_SEQ * HD;
  u16* vtb = vt + (size_t)bh * HD * T_SEQ;
#pragma unroll
  for (int g = 0; g < 2; ++g) {
    int id = g * 256 + tid;
    int r = id >> 3, c = id & 7;
    uint4 raw = *(const uint4*)&vb[(size_t)(t0 + r) * HD + c * 8];
    u16 tmp[8];
    *(uint4*)tmp = raw;
#pragma unroll
    for (int j = 0; j < 8; ++j) tl[r * 65 + c * 8 + j] = tmp[j];
  }
  __syncthreads();
#pragma unroll
  for (int g = 0; g < 2; ++g) {
    int id = g * 256 + tid;
    int d = id >> 3, cw = id & 7;
    u16 tmp[8];
#pragma unroll
    for (int j = 0; j < 8; ++j) tmp[j] = tl[(cw * 8 + j) * 65 + d];
    *(uint4*)&vtb[(size_t)d * T_SEQ + t0 + cw * 8] = *(uint4*)tmp;
  }
}

// ---------------- bf16 GEMM: C = A[M,K] * Bt[N,K]^T + bias ----------------
// 128x128 tile, BK=64, 4 waves (2x2 of 64x64), XOR-swizzled LDS chunks.

#define GEMM_BODY(K)                                                          \
  __shared__ __align__(16) u16 Al[128 * 64];                                  \
  __shared__ __align__(16) u16 Bl[128 * 64];                                  \
  int n0 = blockIdx.x * 128, m0 = blockIdx.y * 128;                           \
  int tid = threadIdx.x, lane = tid & 63;                                     \
  int w = tid >> 6, quad = lane >> 4, l16 = lane & 15;                        \
  int wm = (w >> 1) * 64, wn = (w & 1) * 64;                                  \
  f32x4 acc[4][4];                                                            \
  _Pragma("unroll") for (int a = 0; a < 4; ++a)                               \
      _Pragma("unroll") for (int b = 0; b < 4; ++b)                           \
          acc[a][b] = (f32x4){0.f, 0.f, 0.f, 0.f};                            \
  for (int kt = 0; kt < (K); kt += 64) {                                      \
    __syncthreads();                                                          \
    _Pragma("unroll") for (int g = 0; g < 4; ++g) {                           \
      int id = g * 256 + tid;                                                 \
      int r = id >> 3, c = id & 7, cs = c ^ (r & 7);                          \
      async16(A + (size_t)(m0 + r) * (K) + kt + cs * 8, (char*)Al + id * 16); \
      async16(Bt + (size_t)(n0 + r) * (K) + kt + cs * 8, (char*)Bl + id * 16);\
    }                                                                         \
    __syncthreads();                                                          \
    _Pragma("unroll") for (int s = 0; s < 2; ++s) {                           \
      s16x8 af[4], bfr[4];                                                    \
      _Pragma("unroll") for (int mi = 0; mi < 4; ++mi) {                      \
        int m = wm + mi * 16 + l16;                                           \
        af[mi] = *(const s16x8*)&Al[m * 64 + (((s * 4 + quad) ^ (m & 7)) * 8)];\
      }                                                                       \
      _Pragma("unroll") for (int ni = 0; ni < 4; ++ni) {                      \
        int n = wn + ni * 16 + l16;                                           \
        bfr[ni] = *(const s16x8*)&Bl[n * 64 + (((s * 4 + quad) ^ (n & 7)) * 8)];\
      }                                                                       \
      _Pragma("unroll") for (int mi = 0; mi < 4; ++mi)                        \
          _Pragma("unroll") for (int ni = 0; ni < 4; ++ni)                    \
              acc[mi][ni] = __builtin_amdgcn_mfma_f32_16x16x32_bf16(          \
                  af[mi], bfr[ni], acc[mi][ni], 0, 0, 0);                     \
    }                                                                         \
  }

__global__ __launch_bounds__(256) void k_gemm_qkv(
    const u16* __restrict__ A, const u16* __restrict__ Bt,
    const float* __restrict__ bias, u16* __restrict__ qh,
    u16* __restrict__ kh, u16* __restrict__ vh) {
  GEMM_BODY(C_EMBD)
#pragma unroll
  for (int ni = 0; ni < 4; ++ni) {
    int n = n0 + wn + ni * 16 + l16;
    float bv = bias[n];
    int part = n / C_EMBD;
    int nn = n - part * C_EMBD;
    int hh = nn >> 6, d = nn & 63;
    u16* dst = part == 0 ? qh : (part == 1 ? kh : vh);
#pragma unroll
    for (int mi = 0; mi < 4; ++mi) {
      int mbase = m0 + wm + mi * 16 + quad * 4;
#pragma unroll
      for (int r = 0; r < 4; ++r) {
        int m = mbase + r;
        int b = m >> 11, t = m & 2047;
        dst[((size_t)(b * N_HEADC + hh) * T_SEQ + t) * HD + d] =
            f2bf(acc[mi][ni][r] + bv);
      }
    }
  }
}

// out-proj GEMM: BM=128 x BN=64 -> grid (12,64) = 768 blocks = 3/CU balanced.

__global__ __launch_bounds__(256) void k_gemm_out(
    const u16* __restrict__ A, const u16* __restrict__ Bt,
    const float* __restrict__ bias, float* __restrict__ out) {
  __shared__ __align__(16) u16 Al[128 * 64];
  __shared__ __align__(16) u16 Bl[64 * 64];
  int n0 = blockIdx.x * 64, m0 = blockIdx.y * 128;
  int tid = threadIdx.x, lane = tid & 63;
  int w = tid >> 6, quad = lane >> 4, l16 = lane & 15;
  int wm = (w >> 1) * 64, wn = (w & 1) * 32;
  f32x4 acc[4][2];
#pragma unroll
  for (int a = 0; a < 4; ++a)
#pragma unroll
    for (int b = 0; b < 2; ++b) acc[a][b] = (f32x4){0.f, 0.f, 0.f, 0.f};
  for (int kt = 0; kt < C_EMBD; kt += 64) {
    __syncthreads();
#pragma unroll
    for (int g = 0; g < 4; ++g) {
      int id = g * 256 + tid;
      int r = id >> 3, c = id & 7, cs = c ^ (r & 7);
      async16(A + (size_t)(m0 + r) * C_EMBD + kt + cs * 8, (char*)Al + id * 16);
    }
#pragma unroll
    for (int g = 0; g < 2; ++g) {
      int id = g * 256 + tid;
      int r = id >> 3, c = id & 7, cs = c ^ (r & 7);
      async16(Bt + (size_t)(n0 + r) * C_EMBD + kt + cs * 8, (char*)Bl + id * 16);
    }
    __syncthreads();
#pragma unroll
    for (int s = 0; s < 2; ++s) {
      s16x8 af[4], bfr[2];
#pragma unroll
      for (int mi = 0; mi < 4; ++mi) {
        int m = wm + mi * 16 + l16;
        af[mi] = *(const s16x8*)&Al[m * 64 + (((s * 4 + quad) ^ (m & 7)) * 8)];
      }
#pragma unroll
      for (int ni = 0; ni < 2; ++ni) {
        int n = wn + ni * 16 + l16;
        bfr[ni] = *(const s16x8*)&Bl[n * 64 + (((s * 4 + quad) ^ (n & 7)) * 8)];
      }
#pragma unroll
      for (int mi = 0; mi < 4; ++mi)
#pragma unroll
        for (int ni = 0; ni < 2; ++ni)
          acc[mi][ni] = __builtin_amdgcn_mfma_f32_16x16x32_bf16(
              af[mi], bfr[ni], acc[mi][ni], 0, 0, 0);
    }
  }
#pragma unroll
  for (int ni = 0; ni < 2; ++ni) {
    int n = n0 + wn + ni * 16 + l16;
    float bv = bias[n];
#pragma unroll
    for (int mi = 0; mi < 4; ++mi) {
      int mbase = m0 + wm + mi * 16 + quad * 4;
#pragma unroll
      for (int r = 0; r < 4; ++r)
        out[(size_t)(mbase + r) * C_EMBD + n] = acc[mi][ni][r] + bv;
    }
  }
}

// ---------------- flash attention w/ additive mask ----------------
// v5: BARRIER-FREE, LDS-staging-free. The K-fragment (K[row][quad*8..]) and
// V-fragment (vth[d][k-slice]) are per-lane contiguous 16B global loads, so
// LDS staging (whose only purpose was cross-wave sharing) and its per-tile
// __syncthreads (whose vmcnt(0) drained mask+KV loads every iteration) are
// removed entirely. Every wave free-runs; compiler emits fine-grained counted
// waitcnts for register loads. K/V 4x read amplification is L2-absorbed
// (~25 MB unique vs 147 MB mask HBM). LDS = 8 KB wave-private P staging only;
// 3 waves/SIMD (launch_bounds 256,3) = 12 independent streams/CU (was 3).
// Heavy+light q-tile pairing kept (equal-cost blocks, grid 16x48=768 = 3/CU).

__global__ __launch_bounds__(256, 3) void k_attn(
    const u16* __restrict__ qh, const u16* __restrict__ kh,
    const u16* __restrict__ vth, const float* __restrict__ mask,
    u16* __restrict__ y) {
  __shared__ __align__(16) u16 Pl[4][16 * 64];  // per-wave P staging, swizzled
  int bx0 = blockIdx.x;                    // 0..15
  int by = blockIdx.y;
  int h = by >> 2, b = by & 3;             // same-h batches adjacent: mask L2 reuse
  int bh = b * N_HEADC + h;
  int tid = threadIdx.x, lane = tid & 63;
  int w = tid >> 6, quad = lane >> 4, l16 = lane & 15;

  // per-lane fragment base pointers (K row-major [t][d]; vth [d][t])
  const u16* kb = kh + ((size_t)bh * T_SEQ + l16) * HD + quad * 8;
  const u16* vb = vth + ((size_t)bh * HD + l16) * T_SEQ + quad * 8;

#pragma unroll 1
  for (int ph = 0; ph < 2; ++ph) {
    int bx = ph == 0 ? (31 - bx0) : bx0;   // heavy tile first, then light
    int qw = bx * 64 + w * 16;

    const u16* qg = qh + ((size_t)bh * T_SEQ + qw + l16) * HD;
    s16x8 qf0 = *(const s16x8*)(qg + quad * 8);
    s16x8 qf1 = *(const s16x8*)(qg + 32 + quad * 8);
    const float* mg = mask + ((size_t)h * T_SEQ + qw + quad * 4) * T_SEQ + l16;

    f32x4 yacc[4];
#pragma unroll
    for (int i = 0; i < 4; ++i) yacc[i] = (f32x4){0.f, 0.f, 0.f, 0.f};
    float lsum[4] = {0.f, 0.f, 0.f, 0.f};

    int nkt = bx + 1;

    float mcur[16];
#pragma unroll
    for (int r = 0; r < 4; ++r)
#pragma unroll
      for (int nt = 0; nt < 4; ++nt)
        mcur[r * 4 + nt] = mg[(size_t)r * T_SEQ + nt * 16];

    for (int kt = 0; kt < nkt; ++kt) {
      int ktb = kt * 64;
      // prefetch mask for tile kt+1 into registers (consumed next iteration)
      int nb_m = (kt + 1 < nkt ? kt + 1 : kt) * 64;
      float mnxt[16];
#pragma unroll
      for (int r = 0; r < 4; ++r)
#pragma unroll
        for (int nt = 0; nt < 4; ++nt)
          mnxt[r * 4 + nt] = mg[(size_t)r * T_SEQ + nb_m + nt * 16];

      // S = Q K^T  (16x64 per wave); K fragments direct from global
      f32x4 sacc[4];
#pragma unroll
      for (int nt = 0; nt < 4; ++nt) sacc[nt] = (f32x4){0.f, 0.f, 0.f, 0.f};
      const u16* kpt = kb + (size_t)ktb * HD;
#pragma unroll
      for (int nt = 0; nt < 4; ++nt) {
        s16x8 kf0 = *(const s16x8*)(kpt + nt * 16 * HD);
        s16x8 kf1 = *(const s16x8*)(kpt + nt * 16 * HD + 32);
        sacc[nt] = __builtin_amdgcn_mfma_f32_16x16x32_bf16(qf0, kf0, sacc[nt], 0, 0, 0);
        sacc[nt] = __builtin_amdgcn_mfma_f32_16x16x32_bf16(qf1, kf1, sacc[nt], 0, 0, 0);
      }

      // p = exp(s/8 + mask); per-lane l partials; P -> per-wave LDS (swizzled)
      u16* pw = &Pl[w][0];
#pragma unroll
      for (int r = 0; r < 4; ++r) {
        int prow = quad * 4 + r;
#pragma unroll
        for (int nt = 0; nt < 4; ++nt) {
          float val = __expf(fmaf(sacc[nt][r], 0.125f, mcur[r * 4 + nt]));
          lsum[r] += val;
          u32 u = __builtin_bit_cast(u32, val);
          int chunk = (nt * 2 + (l16 >> 3)) ^ (prow & 7);
          pw[prow * 64 + chunk * 8 + (l16 & 7)] = (u16)((u + 0x8000u) >> 16);
        }
      }
      // wave-local P round-trip: lgkmcnt orders same-wave DS; no barrier

      // Y += P V ; V fragments direct from global (vth: d-major, t contiguous)
      const u16* vpt = vb + ktb;
#pragma unroll
      for (int s = 0; s < 2; ++s) {
        s16x8 pf = *(const s16x8*)&Pl[w][l16 * 64 + (((s * 4 + quad) ^ (l16 & 7)) * 8)];
#pragma unroll
        for (int nt = 0; nt < 4; ++nt) {
          s16x8 vf = *(const s16x8*)(vpt + (size_t)nt * 16 * T_SEQ + s * 32);
          yacc[nt] = __builtin_amdgcn_mfma_f32_16x16x32_bf16(pf, vf, yacc[nt], 0, 0, 0);
        }
      }

      // rotate mask pipeline
#pragma unroll
      for (int i = 0; i < 16; ++i) mcur[i] = mnxt[i];
    }

    // epilogue: reduce l across the 16 lanes holding each row, then y = yacc/l
    u16* yb = y + ((size_t)b * T_SEQ + qw + quad * 4) * C_EMBD + h * HD + l16;
#pragma unroll
    for (int r = 0; r < 4; ++r) {
      float l = lsum[r];
      l += __shfl_xor(l, 1);
      l += __shfl_xor(l, 2);
      l += __shfl_xor(l, 4);
      l += __shfl_xor(l, 8);
      float inv = 1.0f / l;
#pragma unroll
      for (int nt = 0; nt < 4; ++nt)
        yb[(size_t)r * C_EMBD + nt * 16] = f2bf(yacc[nt][r] * inv);
    }
  }
}

// ---------------- launch ----------------

extern "C" void kernel_launch(void* const* d_in, const int* in_sizes, int n_in,
                              void* d_out, int out_size, void* d_ws, size_t ws_size,
                              hipStream_t stream) {
  (void)in_sizes; (void)n_in; (void)out_size; (void)ws_size;
  const float* x      = (const float*)d_in[0];
  const float* maskp  = (const float*)d_in[1];
  const float* W_attn = (const float*)d_in[2];
  const float* b_attn = (const float*)d_in[3];
  const float* W_proj = (const float*)d_in[4];
  const float* b_proj = (const float*)d_in[5];
  float* out = (float*)d_out;

  char* ws = (char*)d_ws;
  u16* xb  = (u16*)(ws + 0);            // 12,582,912 B  (reused as y after GEMM1)
  u16* yb  = xb;
  u16* wat = (u16*)(ws + 12582912);     //  3,538,944 B
  u16* wpt = (u16*)(ws + 16121856);     //  1,179,648 B
  u16* qh  = (u16*)(ws + 17301504);     // 12,582,912 B
  u16* kh  = (u16*)(ws + 29884416);     // 12,582,912 B
  u16* vh  = (u16*)(ws + 42467328);     // 12,582,912 B
  u16* vth = (u16*)(ws + 55050240);     // 12,582,912 B -> total 67,633,152 B

  k_prep<<<6720, 256, 0, stream>>>((const float4*)x, (ushort4*)xb,
                                   W_attn, wat, W_proj, wpt);
  k_gemm_qkv<<<dim3(18, 64), 256, 0, stream>>>(xb, wat, b_attn, qh, kh, vh);
  k_transpose_v<<<dim3(32, 48), 256, 0, stream>>>(vh, vth);
  k_attn<<<dim3(16, 48), 256, 0, stream>>>(qh, kh, vth, maskp, yb);
  k_gemm_out<<<dim3(12, 64), 256, 0, stream>>>(yb, wpt, b_proj, out);
}

// Round 6
// 432.755 us; speedup vs baseline: 1.2575x; 1.2575x over previous
//
#include <hip/hip_runtime.h>
#include <hip/hip_bf16.h>
#include <stdint.h>

#define N_HEADC 12
#define T_SEQ   2048
#define C_EMBD  768
#define HD      64

typedef short s16x8 __attribute__((ext_vector_type(8)));
typedef float f32x4 __attribute__((ext_vector_type(4)));
typedef unsigned short u16;
typedef unsigned int   u32;
typedef unsigned long long u64;

// fp32 -> bf16 round-to-nearest-even
__device__ __forceinline__ u16 f2bf(float f) {
  u32 u = __builtin_bit_cast(u32, f);
  u32 r = (u + 0x7FFFu + ((u >> 16) & 1u)) >> 16;
  return (u16)r;
}

// async 16B global->LDS (dest = wave-uniform base + lane*16)
__device__ __forceinline__ void async16(const void* g, void* l) {
  u64 ga = (u64)g;
  u32 la = (u32)(u64)l;
  __builtin_amdgcn_global_load_lds(
      (const __attribute__((address_space(1))) u32*)ga,
      (__attribute__((address_space(3))) u32*)la, 16, 0, 0);
}

// ---------------- fused prep: cvt + both weight transposes ----------------

__global__ __launch_bounds__(256) void k_prep(
    const float4* __restrict__ x4, ushort4* __restrict__ xb4,
    const float* __restrict__ Wa, u16* __restrict__ wat,
    const float* __restrict__ Wp, u16* __restrict__ wpt) {
  __shared__ float tl[64 * 65];
  int bx = blockIdx.x;
  int tid = threadIdx.x;
  if (bx < 6144) {
    int i = bx * 256 + tid;
    float4 v = x4[i];
    ushort4 o;
    o.x = f2bf(v.x); o.y = f2bf(v.y); o.z = f2bf(v.z); o.w = f2bf(v.w);
    xb4[i] = o;
    return;
  }
  const float* in; u16* out; int Kdim, Ndim, n0, k0;
  if (bx < 6144 + 432) {
    int idx = bx - 6144;
    in = Wa; out = wat; Kdim = C_EMBD; Ndim = 3 * C_EMBD;
    n0 = (idx % 36) * 64; k0 = (idx / 36) * 64;
  } else {
    int idx = bx - 6576;
    in = Wp; out = wpt; Kdim = C_EMBD; Ndim = C_EMBD;
    n0 = (idx % 12) * 64; k0 = (idx / 12) * 64;
  }
  int r0 = tid >> 4;
  int cb = (tid & 15) * 4;
#pragma unroll
  for (int g = 0; g < 4; ++g) {
    int r = r0 + g * 16;
    float4 v = *(const float4*)&in[(size_t)(k0 + r) * Ndim + n0 + cb];
    tl[r * 65 + cb + 0] = v.x;
    tl[r * 65 + cb + 1] = v.y;
    tl[r * 65 + cb + 2] = v.z;
    tl[r * 65 + cb + 3] = v.w;
  }
  __syncthreads();
  int rr0 = tid >> 3;
  int cc = (tid & 7) * 8;
#pragma unroll
  for (int g = 0; g < 2; ++g) {
    int rr = rr0 + g * 32;
    u16 tmp[8];
#pragma unroll
    for (int j = 0; j < 8; ++j) tmp[j] = f2bf(tl[(cc + j) * 65 + rr]);
    *(uint4*)&out[(size_t)(n0 + rr) * Kdim + k0 + cc] = *(uint4*)tmp;
  }
}

// ---------------- bf16 GEMM: C = A[M,K] * Bt[N,K]^T + bias ----------------
// 128x128 tile, BK=64, 4 waves (2x2 of 64x64), XOR-swizzled LDS chunks.

#define GEMM_BODY(K)                                                          \
  __shared__ __align__(16) u16 Al[128 * 64];                                  \
  __shared__ __align__(16) u16 Bl[128 * 64];                                  \
  int n0 = blockIdx.x * 128, m0 = blockIdx.y * 128;                           \
  int tid = threadIdx.x, lane = tid & 63;                                     \
  int w = tid >> 6, quad = lane >> 4, l16 = lane & 15;                        \
  int wm = (w >> 1) * 64, wn = (w & 1) * 64;                                  \
  f32x4 acc[4][4];                                                            \
  _Pragma("unroll") for (int a = 0; a < 4; ++a)                               \
      _Pragma("unroll") for (int b = 0; b < 4; ++b)                           \
          acc[a][b] = (f32x4){0.f, 0.f, 0.f, 0.f};                            \
  for (int kt = 0; kt < (K); kt += 64) {                                      \
    __syncthreads();                                                          \
    _Pragma("unroll") for (int g = 0; g < 4; ++g) {                           \
      int id = g * 256 + tid;                                                 \
      int r = id >> 3, c = id & 7, cs = c ^ (r & 7);                          \
      async16(A + (size_t)(m0 + r) * (K) + kt + cs * 8, (char*)Al + id * 16); \
      async16(Bt + (size_t)(n0 + r) * (K) + kt + cs * 8, (char*)Bl + id * 16);\
    }                                                                         \
    __syncthreads();                                                          \
    _Pragma("unroll") for (int s = 0; s < 2; ++s) {                           \
      s16x8 af[4], bfr[4];                                                    \
      _Pragma("unroll") for (int mi = 0; mi < 4; ++mi) {                      \
        int m = wm + mi * 16 + l16;                                           \
        af[mi] = *(const s16x8*)&Al[m * 64 + (((s * 4 + quad) ^ (m & 7)) * 8)];\
      }                                                                       \
      _Pragma("unroll") for (int ni = 0; ni < 4; ++ni) {                      \
        int n = wn + ni * 16 + l16;                                           \
        bfr[ni] = *(const s16x8*)&Bl[n * 64 + (((s * 4 + quad) ^ (n & 7)) * 8)];\
      }                                                                       \
      _Pragma("unroll") for (int mi = 0; mi < 4; ++mi)                        \
          _Pragma("unroll") for (int ni = 0; ni < 4; ++ni)                    \
              acc[mi][ni] = __builtin_amdgcn_mfma_f32_16x16x32_bf16(          \
                  af[mi], bfr[ni], acc[mi][ni], 0, 0, 0);                     \
    }                                                                         \
  }

// qkv GEMM. V-part of the epilogue writes DIRECTLY in transposed layout
// vth[bh][d][t] (replaces the separate k_transpose_v pass: -50 MB of
// read+write traffic and one launch). Scattered V stores are L2-absorbed.

__global__ __launch_bounds__(256) void k_gemm_qkv(
    const u16* __restrict__ A, const u16* __restrict__ Bt,
    const float* __restrict__ bias, u16* __restrict__ qh,
    u16* __restrict__ kh, u16* __restrict__ vth) {
  GEMM_BODY(C_EMBD)
#pragma unroll
  for (int ni = 0; ni < 4; ++ni) {
    int n = n0 + wn + ni * 16 + l16;
    float bv = bias[n];
    int part = n / C_EMBD;
    int nn = n - part * C_EMBD;
    int hh = nn >> 6, d = nn & 63;
    u16* dst = part == 0 ? qh : kh;
#pragma unroll
    for (int mi = 0; mi < 4; ++mi) {
      int mbase = m0 + wm + mi * 16 + quad * 4;
#pragma unroll
      for (int r = 0; r < 4; ++r) {
        int m = mbase + r;
        int b = m >> 11, t = m & 2047;
        u16 val = f2bf(acc[mi][ni][r] + bv);
        if (part == 2)
          vth[((size_t)(b * N_HEADC + hh) * HD + d) * T_SEQ + t] = val;
        else
          dst[((size_t)(b * N_HEADC + hh) * T_SEQ + t) * HD + d] = val;
      }
    }
  }
}

// out-proj GEMM: BM=128 x BN=64 -> grid (12,64) = 768 blocks = 3/CU balanced.

__global__ __launch_bounds__(256) void k_gemm_out(
    const u16* __restrict__ A, const u16* __restrict__ Bt,
    const float* __restrict__ bias, float* __restrict__ out) {
  __shared__ __align__(16) u16 Al[128 * 64];
  __shared__ __align__(16) u16 Bl[64 * 64];
  int n0 = blockIdx.x * 64, m0 = blockIdx.y * 128;
  int tid = threadIdx.x, lane = tid & 63;
  int w = tid >> 6, quad = lane >> 4, l16 = lane & 15;
  int wm = (w >> 1) * 64, wn = (w & 1) * 32;
  f32x4 acc[4][2];
#pragma unroll
  for (int a = 0; a < 4; ++a)
#pragma unroll
    for (int b = 0; b < 2; ++b) acc[a][b] = (f32x4){0.f, 0.f, 0.f, 0.f};
  for (int kt = 0; kt < C_EMBD; kt += 64) {
    __syncthreads();
#pragma unroll
    for (int g = 0; g < 4; ++g) {
      int id = g * 256 + tid;
      int r = id >> 3, c = id & 7, cs = c ^ (r & 7);
      async16(A + (size_t)(m0 + r) * C_EMBD + kt + cs * 8, (char*)Al + id * 16);
    }
#pragma unroll
    for (int g = 0; g < 2; ++g) {
      int id = g * 256 + tid;
      int r = id >> 3, c = id & 7, cs = c ^ (r & 7);
      async16(Bt + (size_t)(n0 + r) * C_EMBD + kt + cs * 8, (char*)Bl + id * 16);
    }
    __syncthreads();
#pragma unroll
    for (int s = 0; s < 2; ++s) {
      s16x8 af[4], bfr[2];
#pragma unroll
      for (int mi = 0; mi < 4; ++mi) {
        int m = wm + mi * 16 + l16;
        af[mi] = *(const s16x8*)&Al[m * 64 + (((s * 4 + quad) ^ (m & 7)) * 8)];
      }
#pragma unroll
      for (int ni = 0; ni < 2; ++ni) {
        int n = wn + ni * 16 + l16;
        bfr[ni] = *(const s16x8*)&Bl[n * 64 + (((s * 4 + quad) ^ (n & 7)) * 8)];
      }
#pragma unroll
      for (int mi = 0; mi < 4; ++mi)
#pragma unroll
        for (int ni = 0; ni < 2; ++ni)
          acc[mi][ni] = __builtin_amdgcn_mfma_f32_16x16x32_bf16(
              af[mi], bfr[ni], acc[mi][ni], 0, 0, 0);
    }
  }
#pragma unroll
  for (int ni = 0; ni < 2; ++ni) {
    int n = n0 + wn + ni * 16 + l16;
    float bv = bias[n];
#pragma unroll
    for (int mi = 0; mi < 4; ++mi) {
      int mbase = m0 + wm + mi * 16 + quad * 4;
#pragma unroll
      for (int r = 0; r < 4; ++r)
        out[(size_t)(mbase + r) * C_EMBD + n] = acc[mi][ni][r] + bv;
    }
  }
}

// ---------------- flash attention w/ additive mask ----------------
// v4 (REVERTED from v5; v5's direct-global K/V lost prefetch cover and
// regressed 2.3x). LDS K/V double-buffer, one barrier per k-tile, mask
// register pipeline, heavy+light q-tile pairing (equal-cost blocks).

__global__ __launch_bounds__(256, 4) void k_attn(
    const u16* __restrict__ qh, const u16* __restrict__ kh,
    const u16* __restrict__ vth, const float* __restrict__ mask,
    u16* __restrict__ y) {
  __shared__ __align__(16) u16 Kl[2][64 * 64];
  __shared__ __align__(16) u16 Vl[2][64 * 64];
  __shared__ __align__(16) u16 Pl[4][16 * 64];  // per-wave P staging, swizzled
  int bx0 = blockIdx.x;                    // 0..15
  int by = blockIdx.y;
  int h = by >> 2, b = by & 3;             // same-h batches adjacent: mask L2 reuse
  int bh = b * N_HEADC + h;
  int tid = threadIdx.x, lane = tid & 63;
  int w = tid >> 6, quad = lane >> 4, l16 = lane & 15;

  const u16* kg = kh + (size_t)bh * T_SEQ * HD;
  const u16* vg = vth + (size_t)bh * HD * T_SEQ;

  int r_st = tid >> 3, c_st = tid & 7, cs_st = c_st ^ (r_st & 7);
  int r_st2 = r_st + 32, cs_st2 = c_st ^ (r_st2 & 7);
  int id0 = tid * 16, id1 = (256 + tid) * 16;

#pragma unroll 1
  for (int ph = 0; ph < 2; ++ph) {
    int bx = ph == 0 ? (31 - bx0) : bx0;   // heavy tile first, then light
    int qw = bx * 64 + w * 16;

    const u16* qg = qh + ((size_t)bh * T_SEQ + qw + l16) * HD;
    s16x8 qf0 = *(const s16x8*)(qg + quad * 8);
    s16x8 qf1 = *(const s16x8*)(qg + 32 + quad * 8);
    const float* mg = mask + ((size_t)h * T_SEQ + qw + quad * 4) * T_SEQ + l16;

    f32x4 yacc[4];
#pragma unroll
    for (int i = 0; i < 4; ++i) yacc[i] = (f32x4){0.f, 0.f, 0.f, 0.f};
    float lsum[4] = {0.f, 0.f, 0.f, 0.f};

    int nkt = bx + 1;
    // WAR guard: other waves may still be reading LDS from previous phase
    if (ph) __syncthreads();
    // prologue: tile 0 -> buf 0; mask for tile 0 -> registers
    async16(kg + (size_t)r_st * HD + cs_st * 8, (char*)Kl[0] + id0);
    async16(vg + (size_t)r_st * T_SEQ + cs_st * 8, (char*)Vl[0] + id0);
    async16(kg + (size_t)r_st2 * HD + cs_st2 * 8, (char*)Kl[0] + id1);
    async16(vg + (size_t)r_st2 * T_SEQ + cs_st2 * 8, (char*)Vl[0] + id1);

    float mcur[16];
#pragma unroll
    for (int r = 0; r < 4; ++r)
#pragma unroll
      for (int nt = 0; nt < 4; ++nt)
        mcur[r * 4 + nt] = mg[(size_t)r * T_SEQ + nt * 16];

    for (int kt = 0; kt < nkt; ++kt) {
      int cur = kt & 1;
      __syncthreads();  // drains tile-kt K/V + tile-kt mask (full-iter cover)
      if (kt + 1 < nkt) {
        int nb = (kt + 1) * 64;
        async16(kg + (size_t)(nb + r_st) * HD + cs_st * 8, (char*)Kl[1 - cur] + id0);
        async16(vg + (size_t)r_st * T_SEQ + nb + cs_st * 8, (char*)Vl[1 - cur] + id0);
        async16(kg + (size_t)(nb + r_st2) * HD + cs_st2 * 8, (char*)Kl[1 - cur] + id1);
        async16(vg + (size_t)r_st2 * T_SEQ + nb + cs_st2 * 8, (char*)Vl[1 - cur] + id1);
      }
      // prefetch mask for tile kt+1 into registers (consumed next iteration)
      int nb_m = (kt + 1 < nkt ? kt + 1 : kt) * 64;
      float mnxt[16];
#pragma unroll
      for (int r = 0; r < 4; ++r)
#pragma unroll
        for (int nt = 0; nt < 4; ++nt)
          mnxt[r * 4 + nt] = mg[(size_t)r * T_SEQ + nb_m + nt * 16];

      // S = Q K^T  (16x64 per wave)
      f32x4 sacc[4];
#pragma unroll
      for (int nt = 0; nt < 4; ++nt) sacc[nt] = (f32x4){0.f, 0.f, 0.f, 0.f};
#pragma unroll
      for (int nt = 0; nt < 4; ++nt) {
        int row = nt * 16 + l16;
        s16x8 kf0 = *(const s16x8*)&Kl[cur][row * 64 + ((quad ^ (row & 7)) * 8)];
        sacc[nt] = __builtin_amdgcn_mfma_f32_16x16x32_bf16(qf0, kf0, sacc[nt], 0, 0, 0);
        s16x8 kf1 = *(const s16x8*)&Kl[cur][row * 64 + (((4 + quad) ^ (row & 7)) * 8)];
        sacc[nt] = __builtin_amdgcn_mfma_f32_16x16x32_bf16(qf1, kf1, sacc[nt], 0, 0, 0);
      }

      // p = exp(s/8 + mask); per-lane l partials; P -> per-wave LDS (swizzled)
      u16* pw = &Pl[w][0];
#pragma unroll
      for (int r = 0; r < 4; ++r) {
        int prow = quad * 4 + r;
#pragma unroll
        for (int nt = 0; nt < 4; ++nt) {
          float val = __expf(fmaf(sacc[nt][r], 0.125f, mcur[r * 4 + nt]));
          lsum[r] += val;
          u32 u = __builtin_bit_cast(u32, val);
          int chunk = (nt * 2 + (l16 >> 3)) ^ (prow & 7);
          pw[prow * 64 + chunk * 8 + (l16 & 7)] = (u16)((u + 0x8000u) >> 16);
        }
      }
      // wave-local P round-trip: no barrier needed (lgkmcnt orders same-wave DS)

      // Y += P V
#pragma unroll
      for (int s = 0; s < 2; ++s) {
        s16x8 pf = *(const s16x8*)&Pl[w][l16 * 64 + (((s * 4 + quad) ^ (l16 & 7)) * 8)];
#pragma unroll
        for (int nt = 0; nt < 4; ++nt) {
          int row = nt * 16 + l16;
          s16x8 vf = *(const s16x8*)&Vl[cur][row * 64 + (((s * 4 + quad) ^ (row & 7)) * 8)];
          yacc[nt] = __builtin_amdgcn_mfma_f32_16x16x32_bf16(pf, vf, yacc[nt], 0, 0, 0);
        }
      }

      // rotate mask pipeline
#pragma unroll
      for (int i = 0; i < 16; ++i) mcur[i] = mnxt[i];
    }

    // epilogue: reduce l across the 16 lanes holding each row, then y = yacc/l
    u16* yb = y + ((size_t)b * T_SEQ + qw + quad * 4) * C_EMBD + h * HD + l16;
#pragma unroll
    for (int r = 0; r < 4; ++r) {
      float l = lsum[r];
      l += __shfl_xor(l, 1);
      l += __shfl_xor(l, 2);
      l += __shfl_xor(l, 4);
      l += __shfl_xor(l, 8);
      float inv = 1.0f / l;
#pragma unroll
      for (int nt = 0; nt < 4; ++nt)
        yb[(size_t)r * C_EMBD + nt * 16] = f2bf(yacc[nt][r] * inv);
    }
  }
}

// ---------------- launch ----------------

extern "C" void kernel_launch(void* const* d_in, const int* in_sizes, int n_in,
                              void* d_out, int out_size, void* d_ws, size_t ws_size,
                              hipStream_t stream) {
  (void)in_sizes; (void)n_in; (void)out_size; (void)ws_size;
  const float* x      = (const float*)d_in[0];
  const float* maskp  = (const float*)d_in[1];
  const float* W_attn = (const float*)d_in[2];
  const float* b_attn = (const float*)d_in[3];
  const float* W_proj = (const float*)d_in[4];
  const float* b_proj = (const float*)d_in[5];
  float* out = (float*)d_out;

  char* ws = (char*)d_ws;
  u16* xb  = (u16*)(ws + 0);            // 12,582,912 B  (reused as y after GEMM1)
  u16* yb  = xb;
  u16* wat = (u16*)(ws + 12582912);     //  3,538,944 B
  u16* wpt = (u16*)(ws + 16121856);     //  1,179,648 B
  u16* qh  = (u16*)(ws + 17301504);     // 12,582,912 B
  u16* kh  = (u16*)(ws + 29884416);     // 12,582,912 B
  u16* vth = (u16*)(ws + 42467328);     // 12,582,912 B (written transposed by qkv)

  k_prep<<<6720, 256, 0, stream>>>((const float4*)x, (ushort4*)xb,
                                   W_attn, wat, W_proj, wpt);
  k_gemm_qkv<<<dim3(18, 64), 256, 0, stream>>>(xb, wat, b_attn, qh, kh, vth);
  k_attn<<<dim3(16, 48), 256, 0, stream>>>(qh, kh, vth, maskp, yb);
  k_gemm_out<<<dim3(12, 64), 256, 0, stream>>>(yb, wpt, b_proj, out);
}

// Round 7
// 422.127 us; speedup vs baseline: 1.2891x; 1.0252x over previous
//
#include <hip/hip_runtime.h>
#include <hip/hip_bf16.h>
#include <stdint.h>

#define N_HEADC 12
#define T_SEQ   2048
#define C_EMBD  768
#define HD      64

typedef short s16x8 __attribute__((ext_vector_type(8)));
typedef float f32x4 __attribute__((ext_vector_type(4)));
typedef unsigned short u16;
typedef unsigned int   u32;
typedef unsigned long long u64;

// fp32 -> bf16 round-to-nearest-even
__device__ __forceinline__ u16 f2bf(float f) {
  u32 u = __builtin_bit_cast(u32, f);
  u32 r = (u + 0x7FFFu + ((u >> 16) & 1u)) >> 16;
  return (u16)r;
}

// async 16B global->LDS (dest = wave-uniform base + lane*16)
__device__ __forceinline__ void async16(const void* g, void* l) {
  u64 ga = (u64)g;
  u32 la = (u32)(u64)l;
  __builtin_amdgcn_global_load_lds(
      (const __attribute__((address_space(1))) u32*)ga,
      (__attribute__((address_space(3))) u32*)la, 16, 0, 0);
}

// ---------------- fused prep: cvt + both weight transposes ----------------

__global__ __launch_bounds__(256) void k_prep(
    const float4* __restrict__ x4, ushort4* __restrict__ xb4,
    const float* __restrict__ Wa, u16* __restrict__ wat,
    const float* __restrict__ Wp, u16* __restrict__ wpt) {
  __shared__ float tl[64 * 65];
  int bx = blockIdx.x;
  int tid = threadIdx.x;
  if (bx < 6144) {
    int i = bx * 256 + tid;
    float4 v = x4[i];
    ushort4 o;
    o.x = f2bf(v.x); o.y = f2bf(v.y); o.z = f2bf(v.z); o.w = f2bf(v.w);
    xb4[i] = o;
    return;
  }
  const float* in; u16* out; int Kdim, Ndim, n0, k0;
  if (bx < 6144 + 432) {
    int idx = bx - 6144;
    in = Wa; out = wat; Kdim = C_EMBD; Ndim = 3 * C_EMBD;
    n0 = (idx % 36) * 64; k0 = (idx / 36) * 64;
  } else {
    int idx = bx - 6576;
    in = Wp; out = wpt; Kdim = C_EMBD; Ndim = C_EMBD;
    n0 = (idx % 12) * 64; k0 = (idx / 12) * 64;
  }
  int r0 = tid >> 4;
  int cb = (tid & 15) * 4;
#pragma unroll
  for (int g = 0; g < 4; ++g) {
    int r = r0 + g * 16;
    float4 v = *(const float4*)&in[(size_t)(k0 + r) * Ndim + n0 + cb];
    tl[r * 65 + cb + 0] = v.x;
    tl[r * 65 + cb + 1] = v.y;
    tl[r * 65 + cb + 2] = v.z;
    tl[r * 65 + cb + 3] = v.w;
  }
  __syncthreads();
  int rr0 = tid >> 3;
  int cc = (tid & 7) * 8;
#pragma unroll
  for (int g = 0; g < 2; ++g) {
    int rr = rr0 + g * 32;
    u16 tmp[8];
#pragma unroll
    for (int j = 0; j < 8; ++j) tmp[j] = f2bf(tl[(cc + j) * 65 + rr]);
    *(uint4*)&out[(size_t)(n0 + rr) * Kdim + k0 + cc] = *(uint4*)tmp;
  }
}

// vt[bh][d][t] = v[bh][t][d], bf16, 64x64 tiles (stride-65 LDS: conflict-free)
// (restored: the in-GEMM scattered V store cost +17us vs this coalesced pass)
__global__ __launch_bounds__(256) void k_transpose_v(const u16* __restrict__ v,
                                                     u16* __restrict__ vt) {
  __shared__ u16 tl[64 * 65];
  int t0 = blockIdx.x * 64;
  int bh = blockIdx.y;
  int tid = threadIdx.x;
  const u16* vb = v + (size_t)bh * T_SEQ * HD;
  u16* vtb = vt + (size_t)bh * HD * T_SEQ;
#pragma unroll
  for (int g = 0; g < 2; ++g) {
    int id = g * 256 + tid;
    int r = id >> 3, c = id & 7;
    uint4 raw = *(const uint4*)&vb[(size_t)(t0 + r) * HD + c * 8];
    u16 tmp[8];
    *(uint4*)tmp = raw;
#pragma unroll
    for (int j = 0; j < 8; ++j) tl[r * 65 + c * 8 + j] = tmp[j];
  }
  __syncthreads();
#pragma unroll
  for (int g = 0; g < 2; ++g) {
    int id = g * 256 + tid;
    int d = id >> 3, cw = id & 7;
    u16 tmp[8];
#pragma unroll
    for (int j = 0; j < 8; ++j) tmp[j] = tl[(cw * 8 + j) * 65 + d];
    *(uint4*)&vtb[(size_t)d * T_SEQ + t0 + cw * 8] = *(uint4*)tmp;
  }
}

// ---------------- bf16 GEMM: C = A[M,K] * Bt[N,K]^T + bias ----------------
// 128x128 tile, BK=64, 4 waves (2x2 of 64x64), XOR-swizzled LDS chunks.

#define GEMM_BODY(K)                                                          \
  __shared__ __align__(16) u16 Al[128 * 64];                                  \
  __shared__ __align__(16) u16 Bl[128 * 64];                                  \
  int n0 = blockIdx.x * 128, m0 = blockIdx.y * 128;                           \
  int tid = threadIdx.x, lane = tid & 63;                                     \
  int w = tid >> 6, quad = lane >> 4, l16 = lane & 15;                        \
  int wm = (w >> 1) * 64, wn = (w & 1) * 64;                                  \
  f32x4 acc[4][4];                                                            \
  _Pragma("unroll") for (int a = 0; a < 4; ++a)                               \
      _Pragma("unroll") for (int b = 0; b < 4; ++b)                           \
          acc[a][b] = (f32x4){0.f, 0.f, 0.f, 0.f};                            \
  for (int kt = 0; kt < (K); kt += 64) {                                      \
    __syncthreads();                                                          \
    _Pragma("unroll") for (int g = 0; g < 4; ++g) {                           \
      int id = g * 256 + tid;                                                 \
      int r = id >> 3, c = id & 7, cs = c ^ (r & 7);                          \
      async16(A + (size_t)(m0 + r) * (K) + kt + cs * 8, (char*)Al + id * 16); \
      async16(Bt + (size_t)(n0 + r) * (K) + kt + cs * 8, (char*)Bl + id * 16);\
    }                                                                         \
    __syncthreads();                                                          \
    _Pragma("unroll") for (int s = 0; s < 2; ++s) {                           \
      s16x8 af[4], bfr[4];                                                    \
      _Pragma("unroll") for (int mi = 0; mi < 4; ++mi) {                      \
        int m = wm + mi * 16 + l16;                                           \
        af[mi] = *(const s16x8*)&Al[m * 64 + (((s * 4 + quad) ^ (m & 7)) * 8)];\
      }                                                                       \
      _Pragma("unroll") for (int ni = 0; ni < 4; ++ni) {                      \
        int n = wn + ni * 16 + l16;                                           \
        bfr[ni] = *(const s16x8*)&Bl[n * 64 + (((s * 4 + quad) ^ (n & 7)) * 8)];\
      }                                                                       \
      _Pragma("unroll") for (int mi = 0; mi < 4; ++mi)                        \
          _Pragma("unroll") for (int ni = 0; ni < 4; ++ni)                    \
              acc[mi][ni] = __builtin_amdgcn_mfma_f32_16x16x32_bf16(          \
                  af[mi], bfr[ni], acc[mi][ni], 0, 0, 0);                     \
    }                                                                         \
  }

__global__ __launch_bounds__(256) void k_gemm_qkv(
    const u16* __restrict__ A, const u16* __restrict__ Bt,
    const float* __restrict__ bias, u16* __restrict__ qh,
    u16* __restrict__ kh, u16* __restrict__ vh) {
  GEMM_BODY(C_EMBD)
#pragma unroll
  for (int ni = 0; ni < 4; ++ni) {
    int n = n0 + wn + ni * 16 + l16;
    float bv = bias[n];
    int part = n / C_EMBD;
    int nn = n - part * C_EMBD;
    int hh = nn >> 6, d = nn & 63;
    u16* dst = part == 0 ? qh : (part == 1 ? kh : vh);
#pragma unroll
    for (int mi = 0; mi < 4; ++mi) {
      int mbase = m0 + wm + mi * 16 + quad * 4;
#pragma unroll
      for (int r = 0; r < 4; ++r) {
        int m = mbase + r;
        int b = m >> 11, t = m & 2047;
        dst[((size_t)(b * N_HEADC + hh) * T_SEQ + t) * HD + d] =
            f2bf(acc[mi][ni][r] + bv);
      }
    }
  }
}

// out-proj GEMM: BM=128 x BN=64 -> grid (12,64) = 768 blocks = 3/CU balanced.

__global__ __launch_bounds__(256) void k_gemm_out(
    const u16* __restrict__ A, const u16* __restrict__ Bt,
    const float* __restrict__ bias, float* __restrict__ out) {
  __shared__ __align__(16) u16 Al[128 * 64];
  __shared__ __align__(16) u16 Bl[64 * 64];
  int n0 = blockIdx.x * 64, m0 = blockIdx.y * 128;
  int tid = threadIdx.x, lane = tid & 63;
  int w = tid >> 6, quad = lane >> 4, l16 = lane & 15;
  int wm = (w >> 1) * 64, wn = (w & 1) * 32;
  f32x4 acc[4][2];
#pragma unroll
  for (int a = 0; a < 4; ++a)
#pragma unroll
    for (int b = 0; b < 2; ++b) acc[a][b] = (f32x4){0.f, 0.f, 0.f, 0.f};
  for (int kt = 0; kt < C_EMBD; kt += 64) {
    __syncthreads();
#pragma unroll
    for (int g = 0; g < 4; ++g) {
      int id = g * 256 + tid;
      int r = id >> 3, c = id & 7, cs = c ^ (r & 7);
      async16(A + (size_t)(m0 + r) * C_EMBD + kt + cs * 8, (char*)Al + id * 16);
    }
#pragma unroll
    for (int g = 0; g < 2; ++g) {
      int id = g * 256 + tid;
      int r = id >> 3, c = id & 7, cs = c ^ (r & 7);
      async16(Bt + (size_t)(n0 + r) * C_EMBD + kt + cs * 8, (char*)Bl + id * 16);
    }
    __syncthreads();
#pragma unroll
    for (int s = 0; s < 2; ++s) {
      s16x8 af[4], bfr[2];
#pragma unroll
      for (int mi = 0; mi < 4; ++mi) {
        int m = wm + mi * 16 + l16;
        af[mi] = *(const s16x8*)&Al[m * 64 + (((s * 4 + quad) ^ (m & 7)) * 8)];
      }
#pragma unroll
      for (int ni = 0; ni < 2; ++ni) {
        int n = wn + ni * 16 + l16;
        bfr[ni] = *(const s16x8*)&Bl[n * 64 + (((s * 4 + quad) ^ (n & 7)) * 8)];
      }
#pragma unroll
      for (int mi = 0; mi < 4; ++mi)
#pragma unroll
        for (int ni = 0; ni < 2; ++ni)
          acc[mi][ni] = __builtin_amdgcn_mfma_f32_16x16x32_bf16(
              af[mi], bfr[ni], acc[mi][ni], 0, 0, 0);
    }
  }
#pragma unroll
  for (int ni = 0; ni < 2; ++ni) {
    int n = n0 + wn + ni * 16 + l16;
    float bv = bias[n];
#pragma unroll
    for (int mi = 0; mi < 4; ++mi) {
      int mbase = m0 + wm + mi * 16 + quad * 4;
#pragma unroll
      for (int r = 0; r < 4; ++r)
        out[(size_t)(mbase + r) * C_EMBD + n] = acc[mi][ni][r] + bv;
    }
  }
}

// ---------------- flash attention w/ additive mask ----------------
// v6: KVBLK=128. Evidence: attn time == mask-stream time at ~1.4 TB/s across
// all concurrency levels (R0/R1/R5) => DRAM-pattern-limited: 64 rows x 256 B
// per block-iteration = ~49K interleaved 256B-granule streams. 128-wide
// k-tiles double per-row contiguity (512 B) and halve barrier count
// (33 -> 17/block, still exactly equal per block: ceil((32-j)/2)+ceil((j+1)/2)
// = 17 for all j). Over-diagonal half-tiles come out as exp(NEG)=0; fully
// masked sub-tiles skipped wave-uniformly. LDS 72 KB -> 2 blocks/CU.

__global__ __launch_bounds__(256, 2) void k_attn(
    const u16* __restrict__ qh, const u16* __restrict__ kh,
    const u16* __restrict__ vth, const float* __restrict__ mask,
    u16* __restrict__ y) {
  __shared__ __align__(16) u16 Kl[2][128 * 64];   // [k-col][d]
  __shared__ __align__(16) u16 Vl[2][64 * 128];   // [d][k-col]
  __shared__ __align__(16) u16 Pl[4][16 * 64];    // per-wave P staging, swizzled
  int bx0 = blockIdx.x;                    // 0..15
  int by = blockIdx.y;
  int h = by >> 2, b = by & 3;             // same-h batches adjacent: mask L2 reuse
  int bh = b * N_HEADC + h;
  int tid = threadIdx.x, lane = tid & 63;
  int w = tid >> 6, quad = lane >> 4, l16 = lane & 15;

  const u16* kg = kh + (size_t)bh * T_SEQ * HD;
  const u16* vg = vth + (size_t)bh * HD * T_SEQ;

#pragma unroll 1
  for (int ph = 0; ph < 2; ++ph) {
    int bx = ph == 0 ? (31 - bx0) : bx0;   // heavy tile first, then light
    int qw = bx * 64 + w * 16;

    const u16* qg = qh + ((size_t)bh * T_SEQ + qw + l16) * HD;
    s16x8 qf0 = *(const s16x8*)(qg + quad * 8);
    s16x8 qf1 = *(const s16x8*)(qg + 32 + quad * 8);
    const float* mg = mask + ((size_t)h * T_SEQ + qw + quad * 4) * T_SEQ + l16;

    f32x4 yacc[4];
#pragma unroll
    for (int i = 0; i < 4; ++i) yacc[i] = (f32x4){0.f, 0.f, 0.f, 0.f};
    float lsum[4] = {0.f, 0.f, 0.f, 0.f};

    int nkt = (bx + 2) >> 1;               // ceil((bx+1)/2) 128-wide tiles
    // WAR guard: other waves may still be reading LDS from previous phase
    if (ph) __syncthreads();
    // prologue: stage tile 0 (K: 128x64, V: 64x128), mask tile 0 -> regs
#pragma unroll
    for (int g = 0; g < 4; ++g) {
      int id = g * 256 + tid;
      int rk = id >> 3, ck = id & 7, csk = ck ^ (rk & 7);
      async16(kg + (size_t)rk * HD + csk * 8, (char*)Kl[0] + id * 16);
      int rv = id >> 4, cv = id & 15, csv = cv ^ (rv & 15);
      async16(vg + (size_t)rv * T_SEQ + csv * 8, (char*)Vl[0] + id * 16);
    }

    float mcur0[16], mcur1[16];
#pragma unroll
    for (int r = 0; r < 4; ++r)
#pragma unroll
      for (int nt = 0; nt < 4; ++nt)
        mcur0[r * 4 + nt] = mg[(size_t)r * T_SEQ + nt * 16];
    if (64 <= qw + 15) {
#pragma unroll
      for (int r = 0; r < 4; ++r)
#pragma unroll
        for (int nt = 0; nt < 4; ++nt)
          mcur1[r * 4 + nt] = mg[(size_t)r * T_SEQ + 64 + nt * 16];
    }

    for (int kt = 0; kt < nkt; ++kt) {
      int cur = kt & 1;
      __syncthreads();  // drains tile-kt K/V loads (full-iter cover)
      if (kt + 1 < nkt) {
        int nb = (kt + 1) * 128;
#pragma unroll
        for (int g = 0; g < 4; ++g) {
          int id = g * 256 + tid;
          int rk = id >> 3, ck = id & 7, csk = ck ^ (rk & 7);
          async16(kg + (size_t)(nb + rk) * HD + csk * 8, (char*)Kl[1 - cur] + id * 16);
          int rv = id >> 4, cv = id & 15, csv = cv ^ (rv & 15);
          async16(vg + (size_t)rv * T_SEQ + nb + csv * 8, (char*)Vl[1 - cur] + id * 16);
        }
      }
      // prefetch mask for tile kt+1 into registers (consumed next iteration)
      int nkb = (kt + 1 < nkt ? kt + 1 : kt) * 128;
      float mn0[16], mn1[16];
#pragma unroll
      for (int r = 0; r < 4; ++r)
#pragma unroll
        for (int nt = 0; nt < 4; ++nt)
          mn0[r * 4 + nt] = mg[(size_t)r * T_SEQ + nkb + nt * 16];
      if (nkb + 64 <= qw + 15) {
#pragma unroll
        for (int r = 0; r < 4; ++r)
#pragma unroll
          for (int nt = 0; nt < 4; ++nt)
            mn1[r * 4 + nt] = mg[(size_t)r * T_SEQ + nkb + 64 + nt * 16];
      }

      int kb = kt * 128;
#pragma unroll
      for (int sub = 0; sub < 2; ++sub) {
        if (kb + sub * 64 > qw + 15) break;  // wave-uniform: fully-masked half
        const float* mc = sub == 0 ? mcur0 : mcur1;

        // S = Q K^T  (16x64 per wave) from Kl rows sub*64..
        f32x4 sacc[4];
#pragma unroll
        for (int nt = 0; nt < 4; ++nt) sacc[nt] = (f32x4){0.f, 0.f, 0.f, 0.f};
#pragma unroll
        for (int nt = 0; nt < 4; ++nt) {
          int row = sub * 64 + nt * 16 + l16;
          s16x8 kf0 = *(const s16x8*)&Kl[cur][row * 64 + ((quad ^ (row & 7)) * 8)];
          sacc[nt] = __builtin_amdgcn_mfma_f32_16x16x32_bf16(qf0, kf0, sacc[nt], 0, 0, 0);
          s16x8 kf1 = *(const s16x8*)&Kl[cur][row * 64 + (((4 + quad) ^ (row & 7)) * 8)];
          sacc[nt] = __builtin_amdgcn_mfma_f32_16x16x32_bf16(qf1, kf1, sacc[nt], 0, 0, 0);
        }

        // p = exp(s/8 + mask); per-lane l partials; P -> per-wave LDS (swizzled)
        u16* pw = &Pl[w][0];
#pragma unroll
        for (int r = 0; r < 4; ++r) {
          int prow = quad * 4 + r;
#pragma unroll
          for (int nt = 0; nt < 4; ++nt) {
            float val = __expf(fmaf(sacc[nt][r], 0.125f, mc[r * 4 + nt]));
            lsum[r] += val;
            u32 u = __builtin_bit_cast(u32, val);
            int chunk = (nt * 2 + (l16 >> 3)) ^ (prow & 7);
            pw[prow * 64 + chunk * 8 + (l16 & 7)] = (u16)((u + 0x8000u) >> 16);
          }
        }
        // wave-local P round-trip: same-wave DS ordering, no barrier

        // Y += P V  (V rows = d, cols = k; 128-col rows, 16-chunk swizzle)
#pragma unroll
        for (int s = 0; s < 2; ++s) {
          s16x8 pf = *(const s16x8*)&Pl[w][l16 * 64 + (((s * 4 + quad) ^ (l16 & 7)) * 8)];
#pragma unroll
          for (int nt = 0; nt < 4; ++nt) {
            int drow = nt * 16 + l16;
            s16x8 vf = *(const s16x8*)&Vl[cur][drow * 128 +
                (((sub * 8 + s * 4 + quad) ^ (drow & 15)) * 8)];
            yacc[nt] = __builtin_amdgcn_mfma_f32_16x16x32_bf16(pf, vf, yacc[nt], 0, 0, 0);
          }
        }
      }

      // rotate mask pipeline
#pragma unroll
      for (int i = 0; i < 16; ++i) { mcur0[i] = mn0[i]; mcur1[i] = mn1[i]; }
    }

    // epilogue: reduce l across the 16 lanes holding each row, then y = yacc/l
    u16* yb = y + ((size_t)b * T_SEQ + qw + quad * 4) * C_EMBD + h * HD + l16;
#pragma unroll
    for (int r = 0; r < 4; ++r) {
      float l = lsum[r];
      l += __shfl_xor(l, 1);
      l += __shfl_xor(l, 2);
      l += __shfl_xor(l, 4);
      l += __shfl_xor(l, 8);
      float inv = 1.0f / l;
#pragma unroll
      for (int nt = 0; nt < 4; ++nt)
        yb[(size_t)r * C_EMBD + nt * 16] = f2bf(yacc[nt][r] * inv);
    }
  }
}

// ---------------- launch ----------------

extern "C" void kernel_launch(void* const* d_in, const int* in_sizes, int n_in,
                              void* d_out, int out_size, void* d_ws, size_t ws_size,
                              hipStream_t stream) {
  (void)in_sizes; (void)n_in; (void)out_size; (void)ws_size;
  const float* x      = (const float*)d_in[0];
  const float* maskp  = (const float*)d_in[1];
  const float* W_attn = (const float*)d_in[2];
  const float* b_attn = (const float*)d_in[3];
  const float* W_proj = (const float*)d_in[4];
  const float* b_proj = (const float*)d_in[5];
  float* out = (float*)d_out;

  char* ws = (char*)d_ws;
  u16* xb  = (u16*)(ws + 0);            // 12,582,912 B  (reused as y after GEMM1)
  u16* yb  = xb;
  u16* wat = (u16*)(ws + 12582912);     //  3,538,944 B
  u16* wpt = (u16*)(ws + 16121856);     //  1,179,648 B
  u16* qh  = (u16*)(ws + 17301504);     // 12,582,912 B
  u16* kh  = (u16*)(ws + 29884416);     // 12,582,912 B
  u16* vh  = (u16*)(ws + 42467328);     // 12,582,912 B
  u16* vth = (u16*)(ws + 55050240);     // 12,582,912 B -> total 67,633,152 B

  k_prep<<<6720, 256, 0, stream>>>((const float4*)x, (ushort4*)xb,
                                   W_attn, wat, W_proj, wpt);
  k_gemm_qkv<<<dim3(18, 64), 256, 0, stream>>>(xb, wat, b_attn, qh, kh, vh);
  k_transpose_v<<<dim3(32, 48), 256, 0, stream>>>(vh, vth);
  k_attn<<<dim3(16, 48), 256, 0, stream>>>(qh, kh, vth, maskp, yb);
  k_gemm_out<<<dim3(12, 64), 256, 0, stream>>>(yb, wpt, b_proj, out);
}